// Round 1
// 700.197 us; speedup vs baseline: 1.1446x; 1.1446x over previous
//
#include <hip/hip_runtime.h>
#include <stdint.h>

// B=8, N=E=2048.  All-fp16 single-product pipeline:
//  1) Xh = fp16(X), Wh = fp16(W)
//  2) Q = Xh·Wh^T + b   -> fp16 Qh
//  3) S = Qh·Xh^T + gamma -> fp32
//  4) column softmax stats over n (split-8 + combine)
//  5) attn[b,m,e] = exp(S-M)*R -> fp16 (overlays Qh)
//  6) out = Xh·attn^T -> fp32
//
// GEMM: 256x256 tile, BK=64 (2 K-halves of 32), 8 waves (2Mx4N), per-wave
// 128x64 output.  LDS = 128 KiB as 8 x 16 KiB half-regions:
//   region(d, o, kh) = dbuf d in {0,1} x operand o in {A,B} x K-half kh.
// 8-phase-per-2-tiles schedule (T3+T4+T5 from the technique catalog):
// per K-tile t (buf d=t&1), 4 phases; each phase =
//   { ds_read subtile | issue 1 half-stage | s_barrier | setprio(1) 16xMFMA
//     setprio(0) | [P3: counted vmcnt] | s_barrier }.
// Stage schedule (overwrite-safety proven by the phase barriers):
//   P0: A.k1(t+1) -> (d^1,A,1)   [last read of that region was t-1 P2/P3]
//   P1: B.k1(t+1) -> (d^1,B,1)
//   P2: A.k0(t+2) -> (d,A,0)     [this tile's k0 reads retired at P1 barrier]
//   P3: B.k0(t+2) -> (d,B,0)
// One s_waitcnt vmcnt(4) at P3 leaves exactly the 2 newest half-stages
// (= k0(t+2)) in flight and guarantees ALL of tile t+1 (k0 issued at t-1
// P2/P3, k1 issued at t P0/P1) has landed.  vmcnt(0) only at t=NT-2.
//
// LDS bank-conflict swizzle (unchanged from 128^2 kernel, measured 0
// conflicts): rows are 64 B = 16 banks, rows r,r+2 alias.  Store 16-B segment
// s_lds = s_g ^ ((r>>1)&3) -- applied on the GLOBAL fetch address because
// global_load_lds forces LDS dest = base + lane*16 -- read with the inverse.
//
// Numerics identical to previous kernel (same fp16 products, same fp32 MFMA
// accumulation order over k): absmax ~0.109, threshold 0.205.

typedef _Float16 f16;
typedef f16 f16x8 __attribute__((ext_vector_type(8)));
typedef f16 f16x4 __attribute__((ext_vector_type(4)));
typedef float f32x4 __attribute__((ext_vector_type(4)));

#define ND 2048
#define NNL 4194304L  // ND*ND
#define NT 32         // K tiles of 64

static __device__ __forceinline__ void stage16(const void* g, void* l) {
  __builtin_amdgcn_global_load_lds(
      (const __attribute__((address_space(1))) uint32_t*)g,
      (__attribute__((address_space(3))) uint32_t*)l, 16, 0, 0);
}

// ---------------- fp32 -> fp16 convert ----------------
__global__ void cvt_f16(const float* __restrict__ x, f16* __restrict__ h, int n4) {
  int i = blockIdx.x * 256 + threadIdx.x;
  if (i >= n4) return;
  float4 v = reinterpret_cast<const float4*>(x)[i];
  f16x4 o;
  o.x = (f16)v.x; o.y = (f16)v.y; o.z = (f16)v.z; o.w = (f16)v.w;
  reinterpret_cast<f16x4*>(h)[i] = o;
}

// region byte base within smem: d=dbuf(0/1), o=op(0=A,1=B), kh=K-half(0/1)
#define RB(d_, o_, kh_) ((((d_) << 2) | ((o_) << 1) | (kh_)) * 16384)

// stage one 16 KiB half-region (256 rows x 32 f16): 2 x 8 KiB load-rounds.
// gp_ already folds in (row = tid>>2, seg s_g); l=1 adds 128 rows.
#define STG(gp_, ro_, t_, kh_)                                           \
  do {                                                                   \
    stage16((gp_) + (long)(t_) * 128 + (kh_) * 64, smem + (ro_) + ld0);  \
    stage16((gp_) + 524288L + (long)(t_) * 128 + (kh_) * 64,             \
            smem + (ro_) + ld1);                                         \
  } while (0)

#define FENCE asm volatile("" ::: "memory")

// One phase: mh_ = M-half (A frags mh_*4 .. mh_*4+3), kh_ = K-half.
// RDB_=1 also (re)loads the 4 B frags (reused by the following mh_=1 phase).
#define PHASE(d_, mh_, kh_, RDB_, STAGE_, WAIT_)                              \
  do {                                                                        \
    const char* ra_ = smem + RB(d_, 0, kh_) + (mh_) * 4096 + aoff;            \
    f16x8 af[4];                                                              \
    af[0] = *(const f16x8*)(ra_);                                             \
    af[1] = *(const f16x8*)(ra_ + 1024);                                      \
    af[2] = *(const f16x8*)(ra_ + 2048);                                      \
    af[3] = *(const f16x8*)(ra_ + 3072);                                      \
    if (RDB_) {                                                               \
      const char* rb_ = smem + RB(d_, 1, kh_) + boff;                         \
      bf[0] = *(const f16x8*)(rb_);                                           \
      bf[1] = *(const f16x8*)(rb_ + 1024);                                    \
      bf[2] = *(const f16x8*)(rb_ + 2048);                                    \
      bf[3] = *(const f16x8*)(rb_ + 3072);                                    \
    }                                                                         \
    STAGE_                                                                    \
    FENCE;                                                                    \
    __builtin_amdgcn_s_barrier();                                             \
    FENCE;                                                                    \
    __builtin_amdgcn_s_setprio(1);                                            \
    _Pragma("unroll") for (int mt_ = 0; mt_ < 4; ++mt_) {                     \
      _Pragma("unroll") for (int nt_ = 0; nt_ < 4; ++nt_) {                   \
        acc[(mh_) * 4 + mt_][nt_] = __builtin_amdgcn_mfma_f32_16x16x32_f16(   \
            af[mt_], bf[nt_], acc[(mh_) * 4 + mt_][nt_], 0, 0, 0);            \
      }                                                                       \
    }                                                                         \
    __builtin_amdgcn_s_setprio(0);                                            \
    WAIT_                                                                     \
    FENCE;                                                                    \
    __builtin_amdgcn_s_barrier();                                             \
    FENCE;                                                                    \
  } while (0)

// ---------------- GEMM: C[i,j] = dot(A[i,:], B[j,:])  (row-major, K=2048)
// MODE 1: epilogue + bias[j], fp16 store;  MODE 0: + gamma scalar, fp32 store
template <int MODE>
__launch_bounds__(512, 2) __global__
void gemm256(const f16* __restrict__ A, long sA, const f16* __restrict__ B, long sB,
             const float* __restrict__ bias, const float* __restrict__ gamma,
             float* __restrict__ Cf, f16* __restrict__ Ch) {
  __shared__ char smem[131072];

  const int bz = blockIdx.z;
  const long tm = (long)blockIdx.y * 256;
  const long tn = (long)blockIdx.x * 256;
  const int tid = threadIdx.x;
  const int lane = tid & 63;
  const int wid = tid >> 6;
  const int wm = (wid >> 2) << 7;  // 0 / 128
  const int wn = (wid & 3) << 6;   // 0 / 64 / 128 / 192

  // staging: linear idx16 = l*512 + tid -> row = idx>>2, s_lds = idx&3,
  // fetch global seg s_g = s_lds ^ ((row>>1)&3) = (tid&3)^((tid>>3)&3)
  // (identical for both l since 512 and 64 are multiples of 32).
  const int sg = (tid & 3) ^ ((tid >> 3) & 3);
  const char* gA = (const char*)(A + bz * sA + tm * ND) + (long)(tid >> 2) * 4096 + sg * 16;
  const char* gB = (const char*)(B + bz * sB + tn * ND) + (long)(tid >> 2) * 4096 + sg * 16;
  const uint32_t ld0 = tid * 16u;
  const uint32_t ld1 = 8192u + tid * 16u;

  // reader: row = base16 + (lane&15); LDS seg = (lane>>4) ^ ((row>>1)&3)
  const int segsw = (((lane >> 4) ^ ((lane >> 1) & 3)) << 4);  // bytes
  const int lrow = lane & 15;
  const int aoff = (wm + lrow) * 64 + segsw;
  const int boff = (wn + lrow) * 64 + segsw;

  f32x4 acc[8][4] = {};
  f16x8 bf[4];

  // prologue: tile0 fully + tile1 k0; wait leaves the 2 newest halves in flight
  STG(gA, RB(0, 0, 0), 0, 0);
  STG(gB, RB(0, 1, 0), 0, 0);
  STG(gA, RB(0, 0, 1), 0, 1);
  STG(gB, RB(0, 1, 1), 0, 1);
  STG(gA, RB(1, 0, 0), 1, 0);
  STG(gB, RB(1, 1, 0), 1, 0);
  asm volatile("s_waitcnt vmcnt(4)" ::: "memory");
  __builtin_amdgcn_s_barrier();
  FENCE;

#pragma unroll 2
  for (int t = 0; t < NT; ++t) {
    const int d = t & 1;
    const int e = d ^ 1;
    PHASE(d, 0, 0, 1, if (t + 1 < NT) STG(gA, RB(e, 0, 1), t + 1, 1);, ;);
    PHASE(d, 1, 0, 0, if (t + 1 < NT) STG(gB, RB(e, 1, 1), t + 1, 1);, ;);
    PHASE(d, 0, 1, 1, if (t + 2 < NT) STG(gA, RB(d, 0, 0), t + 2, 0);, ;);
    PHASE(d, 1, 1, 0, if (t + 2 < NT) STG(gB, RB(d, 1, 0), t + 2, 0);,
          if (t + 2 < NT) { asm volatile("s_waitcnt vmcnt(4)" ::: "memory"); }
          else            { asm volatile("s_waitcnt vmcnt(0)" ::: "memory"); });
  }

  // epilogue: C/D layout col=lane&15, row=(lane>>4)*4+reg  [verified m89/m91]
  const int rr = (lane >> 4) << 2;
  const int cc = lane & 15;
  const long cb = (long)bz * NNL;
  if constexpr (MODE == 1) {
#pragma unroll
    for (int nt = 0; nt < 4; ++nt) {
      const long col = tn + wn + nt * 16 + cc;
      const float bj = bias[col];
#pragma unroll
      for (int mt = 0; mt < 8; ++mt) {
#pragma unroll
        for (int r = 0; r < 4; ++r) {
          const long row = tm + wm + mt * 16 + rr + r;
          Ch[cb + row * ND + col] = (f16)(acc[mt][nt][r] + bj);
        }
      }
    }
  } else {
    const float g = gamma ? gamma[0] : 0.0f;
#pragma unroll
    for (int mt = 0; mt < 8; ++mt) {
#pragma unroll
      for (int nt = 0; nt < 4; ++nt) {
#pragma unroll
        for (int r = 0; r < 4; ++r) {
          const long row = tm + wm + mt * 16 + rr + r;
          const long col = tn + wn + nt * 16 + cc;
          Cf[cb + row * ND + col] = acc[mt][nt][r] + g;
        }
      }
    }
  }
}

// ---------------- column-softmax stats (reduce over n, per column m) ----------
__global__ void stats_partial(const float* __restrict__ S, float* __restrict__ Mp,
                              float* __restrict__ Sp) {
  const int col = blockIdx.x * 256 + threadIdx.x;  // 0..2047
  const int seg = blockIdx.y;                      // 0..7 (n-split)
  const int b = blockIdx.z;
  const float* p = S + (long)b * NNL + (long)seg * 256 * ND + col;
  float m = -3.4e38f, s = 0.f;
  for (int n = 0; n < 256; ++n) {
    float x = p[(long)n * ND];
    float nm = fmaxf(m, x);
    s = s * __expf(m - nm) + __expf(x - nm);
    m = nm;
  }
  const long o = ((long)b * 8 + seg) * ND + col;
  Mp[o] = m;
  Sp[o] = s;
}

__global__ void stats_combine(const float* __restrict__ Mp, const float* __restrict__ Sp,
                              float* __restrict__ Mx, float* __restrict__ Rs) {
  const int col = blockIdx.x * 256 + threadIdx.x;
  const int b = blockIdx.y;
  float m = -3.4e38f, s = 0.f;
  for (int k = 0; k < 8; ++k) {
    const long o = ((long)b * 8 + k) * ND + col;
    float mk = Mp[o], sk = Sp[o];
    float nm = fmaxf(m, mk);
    s = s * __expf(m - nm) + sk * __expf(mk - nm);
    m = nm;
  }
  Mx[(long)b * ND + col] = m;
  Rs[(long)b * ND + col] = 1.0f / s;
}

// attn[b,m,e] = exp(S[b,m,e] - Mx[b,e]) * Rs[b,e]  -> fp16, same layout as S
__global__ void scale_exp_kernel(const float* __restrict__ S, const float* __restrict__ Mx,
                                 const float* __restrict__ Rs, f16* __restrict__ A) {
  const long i4 = (long)blockIdx.x * 256 + threadIdx.x;  // total/4
  const long i = i4 * 4;
  const int b = (int)(i >> 22);     // N*N = 2^22
  const int col = (int)(i & 2047);  // e index (multiple of 4)
  float4 s = reinterpret_cast<const float4*>(S)[i4];
  float4 m4 = *reinterpret_cast<const float4*>(&Mx[(long)b * ND + col]);
  float4 r4 = *reinterpret_cast<const float4*>(&Rs[(long)b * ND + col]);
  f16x4 o;
  o.x = (f16)(__expf(s.x - m4.x) * r4.x);
  o.y = (f16)(__expf(s.y - m4.y) * r4.y);
  o.z = (f16)(__expf(s.z - m4.z) * r4.z);
  o.w = (f16)(__expf(s.w - m4.w) * r4.w);
  reinterpret_cast<f16x4*>(A)[i4] = o;
}

// ---------------- launch ----------------
extern "C" void kernel_launch(void* const* d_in, const int* in_sizes, int n_in,
                              void* d_out, int out_size, void* d_ws, size_t ws_size,
                              hipStream_t stream) {
  (void)in_sizes; (void)n_in; (void)out_size;
  const float* X = (const float*)d_in[0];      // [8,2048,2048]
  const float* W = (const float*)d_in[1];      // [2048,2048]
  const float* bias = (const float*)d_in[2];   // [2048]
  const float* gamma = (const float*)d_in[3];  // scalar

  char* ws = (char*)d_ws;
  f16* Xh = (f16*)(ws);                      // 67,108,864 B
  f16* Wh = (f16*)(ws + 67108864L);          //  8,388,608 B
  f16* Qh = (f16*)(ws + 75497472L);          // 67,108,864 B
  float* S = (float*)(ws + 142606336L);      // 134,217,728 B
  float* Mp = (float*)(ws + 276824064L);     //    524,288 B
  float* Sp = (float*)(ws + 277348352L);     //    524,288 B
  float* Mx = (float*)(ws + 277872640L);     //     65,536 B
  float* Rs = (float*)(ws + 277938176L);     //     65,536 B
  f16* Amat = Qh;  // overlay: Q dead after GEMM2 (stream-ordered)
  if (ws_size < 278003712UL) return;

  cvt_f16<<<32768, 256, 0, stream>>>(X, Xh, 8388608);
  cvt_f16<<<4096, 256, 0, stream>>>(W, Wh, 1048576);

  dim3 gg(8, 8, 8), bb(512);
  // Q[b,n,f] = sum_e X[b,n,e] W[f,e] + bias[f]  -> fp16
  gemm256<1><<<gg, bb, 0, stream>>>(Xh, NNL, Wh, 0L, bias, nullptr, nullptr, Qh);
  // S[b,n,m] = sum_e Q[b,n,e] X[b,m,e] + gamma  -> fp32
  gemm256<0><<<gg, bb, 0, stream>>>(Qh, NNL, Xh, NNL, nullptr, gamma, S, nullptr);
  stats_partial<<<dim3(8, 8, 8), 256, 0, stream>>>(S, Mp, Sp);
  stats_combine<<<dim3(8, 8), 256, 0, stream>>>(Mp, Sp, Mx, Rs);
  scale_exp_kernel<<<32768, 256, 0, stream>>>(S, Mx, Rs, Amat);
  // out[b,n,m] = sum_e X[b,n,e] attn[b,m,e]  -> fp32 d_out
  gemm256<0><<<gg, bb, 0, stream>>>(Xh, NNL, Amat, NNL, nullptr, nullptr,
                                    (float*)d_out, nullptr);
}

// Round 2
// 692.889 us; speedup vs baseline: 1.1566x; 1.0105x over previous
//
#include <hip/hip_runtime.h>
#include <stdint.h>

// B=8, N=E=2048.  All-fp16 single-product pipeline:
//  1) Xh = fp16(X), Wh = fp16(W)
//  2) Q = Xh·Wh^T + b   -> fp16 Qh
//  3) S = Qh·Xh^T + gamma -> fp32
//  4) column softmax stats over n (split-8 + combine)
//  5) attn[b,m,e] = exp(S-M)*R -> fp16 (overlays Qh)
//  6) out = Xh·attn^T -> fp32
//
// GEMM: 256x256 tile, BK=64 (2 K-halves of 32), 8 waves (2Mx4N), per-wave
// 128x64 output.  LDS = 128 KiB as 8 x 16 KiB half-regions:
//   region(d, o, kh) = dbuf d in {0,1} x operand o in {A,B} x K-half kh.
//
// R2 schedule: 4 phases/tile but only TWO barriers + TWO counted vmcnt waits
// per tile (R1 had 8 barriers + one shallow vmcnt(4); MfmaUtil 39%, phase
// ~400cy vs ~155cy MFMA -- the gap was barrier lockstep + waiting on loads
// only 2 phases old).  Region lifetime analysis:
//   (d,*,k0): staged t-2 P2/P3, read t P0/P1, overwritten t P2/P3
//   (e,*,k1): staged t   P0/P1, read t+1 P2/P3
// => barrier needed only at end-P1 (reads of k0 retired before overwrite
//    issue at P2) and end-P3 (tile boundary).  Explicit lgkmcnt(0) folded
//    into the pre-barrier waitcnt makes read-retirement airtight.
// vmcnt ledger (loads, 2 per STG; all waves follow identical schedule and
// meet at the barrier, so per-wave vmcnt + barrier = collective guarantee):
//   end-P1: outstanding {t.k1(4), t+1.k0(4), t+1.k1(4)} -> vmcnt(8) drains
//           t.k1 (issued t-1 P0/P1, age 4-5 phases) before P2 reads it.
//   end-P3: outstanding {t+1.k0(4), t+1.k1(4), t+2.k0(4)} -> vmcnt(8) drains
//           t+1.k0 (issued t-1 P2/P3) before t+1 P0 reads it.
//   Tail: t=NT-2 P3 -> vmcnt(4);  t=NT-1 P1 -> vmcnt(0);  t=NT-1 P3 -> none.
// Steady state keeps 8 loads in flight, never drains to 0 in the main loop.
//
// LDS bank-conflict swizzle (measured 0 conflicts): rows are 64 B = 16 banks,
// rows r,r+2 alias.  Store 16-B segment s_lds = s_g ^ ((r>>1)&3) -- applied
// on the GLOBAL fetch address because global_load_lds forces LDS dest =
// base + lane*16 -- and read with the inverse.
//
// Numerics identical (same fp16 products, same fp32 MFMA accumulation order):
// absmax ~0.109, threshold 0.205.  Any absmax change => race, revert.

typedef _Float16 f16;
typedef f16 f16x8 __attribute__((ext_vector_type(8)));
typedef f16 f16x4 __attribute__((ext_vector_type(4)));
typedef float f32x4 __attribute__((ext_vector_type(4)));

#define ND 2048
#define NNL 4194304L  // ND*ND
#define NT 32         // K tiles of 64

static __device__ __forceinline__ void stage16(const void* g, void* l) {
  __builtin_amdgcn_global_load_lds(
      (const __attribute__((address_space(1))) uint32_t*)g,
      (__attribute__((address_space(3))) uint32_t*)l, 16, 0, 0);
}

// ---------------- fp32 -> fp16 convert ----------------
__global__ void cvt_f16(const float* __restrict__ x, f16* __restrict__ h, int n4) {
  int i = blockIdx.x * 256 + threadIdx.x;
  if (i >= n4) return;
  float4 v = reinterpret_cast<const float4*>(x)[i];
  f16x4 o;
  o.x = (f16)v.x; o.y = (f16)v.y; o.z = (f16)v.z; o.w = (f16)v.w;
  reinterpret_cast<f16x4*>(h)[i] = o;
}

// region byte base within smem: d=dbuf(0/1), o=op(0=A,1=B), kh=K-half(0/1)
#define RB(d_, o_, kh_) ((((d_) << 2) | ((o_) << 1) | (kh_)) * 16384)

// stage one 16 KiB half-region (256 rows x 32 f16): 2 x 8 KiB load-rounds.
#define STG(gp_, ro_, t_, kh_)                                           \
  do {                                                                   \
    stage16((gp_) + (long)(t_) * 128 + (kh_) * 64, smem + (ro_) + ld0);  \
    stage16((gp_) + 524288L + (long)(t_) * 128 + (kh_) * 64,             \
            smem + (ro_) + ld1);                                         \
  } while (0)

#define FENCE asm volatile("" ::: "memory")

// waitcnt + barrier: lgkmcnt(0) guarantees this wave's ds_reads are retired
// before it passes the barrier (so post-barrier DMA overwrites are safe);
// vmcnt(N) implements the counted-prefetch ledger above.
#define SYNC(vm_)                                                        \
  do {                                                                   \
    asm volatile("s_waitcnt vmcnt(" #vm_ ") lgkmcnt(0)" ::: "memory");   \
    __builtin_amdgcn_s_barrier();                                        \
    FENCE;                                                               \
  } while (0)

// One phase (no barriers inside): mh_ = M-half, kh_ = K-half.
// RDB_=1 also (re)loads the 4 B frags (reused by the following mh_=1 phase).
#define PHASE(d_, mh_, kh_, RDB_, STAGE_)                                     \
  do {                                                                        \
    const char* ra_ = smem + RB(d_, 0, kh_) + (mh_) * 4096 + aoff;            \
    f16x8 af[4];                                                              \
    af[0] = *(const f16x8*)(ra_);                                             \
    af[1] = *(const f16x8*)(ra_ + 1024);                                      \
    af[2] = *(const f16x8*)(ra_ + 2048);                                      \
    af[3] = *(const f16x8*)(ra_ + 3072);                                      \
    if (RDB_) {                                                               \
      const char* rb_ = smem + RB(d_, 1, kh_) + boff;                         \
      bf[0] = *(const f16x8*)(rb_);                                           \
      bf[1] = *(const f16x8*)(rb_ + 1024);                                    \
      bf[2] = *(const f16x8*)(rb_ + 2048);                                    \
      bf[3] = *(const f16x8*)(rb_ + 3072);                                    \
    }                                                                         \
    STAGE_                                                                    \
    __builtin_amdgcn_s_setprio(1);                                            \
    _Pragma("unroll") for (int mt_ = 0; mt_ < 4; ++mt_) {                     \
      _Pragma("unroll") for (int nt_ = 0; nt_ < 4; ++nt_) {                   \
        acc[(mh_) * 4 + mt_][nt_] = __builtin_amdgcn_mfma_f32_16x16x32_f16(   \
            af[mt_], bf[nt_], acc[(mh_) * 4 + mt_][nt_], 0, 0, 0);            \
      }                                                                       \
    }                                                                         \
    __builtin_amdgcn_s_setprio(0);                                            \
  } while (0)

// ---------------- GEMM: C[i,j] = dot(A[i,:], B[j,:])  (row-major, K=2048)
// MODE 1: epilogue + bias[j], fp16 store;  MODE 0: + gamma scalar, fp32 store
template <int MODE>
__launch_bounds__(512, 2) __global__
void gemm256(const f16* __restrict__ A, long sA, const f16* __restrict__ B, long sB,
             const float* __restrict__ bias, const float* __restrict__ gamma,
             float* __restrict__ Cf, f16* __restrict__ Ch) {
  __shared__ char smem[131072];

  const int bz = blockIdx.z;
  const long tm = (long)blockIdx.y * 256;
  const long tn = (long)blockIdx.x * 256;
  const int tid = threadIdx.x;
  const int lane = tid & 63;
  const int wid = tid >> 6;
  const int wm = (wid >> 2) << 7;  // 0 / 128
  const int wn = (wid & 3) << 6;   // 0 / 64 / 128 / 192

  // staging: linear idx16 = l*512 + tid -> row = idx>>2, s_lds = idx&3,
  // fetch global seg s_g = s_lds ^ ((row>>1)&3) = (tid&3)^((tid>>3)&3)
  const int sg = (tid & 3) ^ ((tid >> 3) & 3);
  const char* gA = (const char*)(A + bz * sA + tm * ND) + (long)(tid >> 2) * 4096 + sg * 16;
  const char* gB = (const char*)(B + bz * sB + tn * ND) + (long)(tid >> 2) * 4096 + sg * 16;
  const uint32_t ld0 = tid * 16u;
  const uint32_t ld1 = 8192u + tid * 16u;

  // reader: row = base16 + (lane&15); LDS seg = (lane>>4) ^ ((row>>1)&3)
  const int segsw = (((lane >> 4) ^ ((lane >> 1) & 3)) << 4);  // bytes
  const int lrow = lane & 15;
  const int aoff = (wm + lrow) * 64 + segsw;
  const int boff = (wn + lrow) * 64 + segsw;

  f32x4 acc[8][4] = {};
  f16x8 bf[4];

  // prologue: t0.k0, t0.k1, t1.k0 (12 loads); vmcnt(8) drains t0.k0 only,
  // leaving {t0.k1, t1.k0} = 8 in flight = steady state.
  STG(gA, RB(0, 0, 0), 0, 0);
  STG(gB, RB(0, 1, 0), 0, 0);
  STG(gA, RB(0, 0, 1), 0, 1);
  STG(gB, RB(0, 1, 1), 0, 1);
  STG(gA, RB(1, 0, 0), 1, 0);
  STG(gB, RB(1, 1, 0), 1, 0);
  asm volatile("s_waitcnt vmcnt(8)" ::: "memory");
  __builtin_amdgcn_s_barrier();
  FENCE;

#pragma unroll 2
  for (int t = 0; t < NT - 2; ++t) {
    const int d = t & 1;
    const int e = d ^ 1;
    PHASE(d, 0, 0, 1, STG(gA, RB(e, 0, 1), t + 1, 1););
    PHASE(d, 1, 0, 0, STG(gB, RB(e, 1, 1), t + 1, 1););
    SYNC(8);
    PHASE(d, 0, 1, 1, STG(gA, RB(d, 0, 0), t + 2, 0););
    PHASE(d, 1, 1, 0, STG(gB, RB(d, 1, 0), t + 2, 0););
    SYNC(8);
  }
  {  // t = NT-2 (even => d=0, e=1)
    PHASE(0, 0, 0, 1, STG(gA, RB(1, 0, 1), NT - 1, 1););
    PHASE(0, 1, 0, 0, STG(gB, RB(1, 1, 1), NT - 1, 1););
    SYNC(8);
    PHASE(0, 0, 1, 1, ;);
    PHASE(0, 1, 1, 0, ;);
    SYNC(4);  // drains (NT-1).k0; leaves (NT-1).k1 in flight
  }
  {  // t = NT-1 (odd => d=1)
    PHASE(1, 0, 0, 1, ;);
    PHASE(1, 1, 0, 0, ;);
    SYNC(0);  // drains (NT-1).k1 before its P2/P3 reads
    PHASE(1, 0, 1, 1, ;);
    PHASE(1, 1, 1, 0, ;);
    // no sync: epilogue uses registers only
  }

  // epilogue: C/D layout col=lane&15, row=(lane>>4)*4+reg  [verified m89/m91]
  const int rr = (lane >> 4) << 2;
  const int cc = lane & 15;
  const long cb = (long)bz * NNL;
  if constexpr (MODE == 1) {
#pragma unroll
    for (int nt = 0; nt < 4; ++nt) {
      const long col = tn + wn + nt * 16 + cc;
      const float bj = bias[col];
#pragma unroll
      for (int mt = 0; mt < 8; ++mt) {
#pragma unroll
        for (int r = 0; r < 4; ++r) {
          const long row = tm + wm + mt * 16 + rr + r;
          Ch[cb + row * ND + col] = (f16)(acc[mt][nt][r] + bj);
        }
      }
    }
  } else {
    const float g = gamma ? gamma[0] : 0.0f;
#pragma unroll
    for (int mt = 0; mt < 8; ++mt) {
#pragma unroll
      for (int nt = 0; nt < 4; ++nt) {
#pragma unroll
        for (int r = 0; r < 4; ++r) {
          const long row = tm + wm + mt * 16 + rr + r;
          const long col = tn + wn + nt * 16 + cc;
          Cf[cb + row * ND + col] = acc[mt][nt][r] + g;
        }
      }
    }
  }
}

// ---------------- column-softmax stats (reduce over n, per column m) ----------
__global__ void stats_partial(const float* __restrict__ S, float* __restrict__ Mp,
                              float* __restrict__ Sp) {
  const int col = blockIdx.x * 256 + threadIdx.x;  // 0..2047
  const int seg = blockIdx.y;                      // 0..7 (n-split)
  const int b = blockIdx.z;
  const float* p = S + (long)b * NNL + (long)seg * 256 * ND + col;
  float m = -3.4e38f, s = 0.f;
  for (int n = 0; n < 256; ++n) {
    float x = p[(long)n * ND];
    float nm = fmaxf(m, x);
    s = s * __expf(m - nm) + __expf(x - nm);
    m = nm;
  }
  const long o = ((long)b * 8 + seg) * ND + col;
  Mp[o] = m;
  Sp[o] = s;
}

__global__ void stats_combine(const float* __restrict__ Mp, const float* __restrict__ Sp,
                              float* __restrict__ Mx, float* __restrict__ Rs) {
  const int col = blockIdx.x * 256 + threadIdx.x;
  const int b = blockIdx.y;
  float m = -3.4e38f, s = 0.f;
  for (int k = 0; k < 8; ++k) {
    const long o = ((long)b * 8 + k) * ND + col;
    float mk = Mp[o], sk = Sp[o];
    float nm = fmaxf(m, mk);
    s = s * __expf(m - nm) + sk * __expf(mk - nm);
    m = nm;
  }
  Mx[(long)b * ND + col] = m;
  Rs[(long)b * ND + col] = 1.0f / s;
}

// attn[b,m,e] = exp(S[b,m,e] - Mx[b,e]) * Rs[b,e]  -> fp16, same layout as S
__global__ void scale_exp_kernel(const float* __restrict__ S, const float* __restrict__ Mx,
                                 const float* __restrict__ Rs, f16* __restrict__ A) {
  const long i4 = (long)blockIdx.x * 256 + threadIdx.x;  // total/4
  const long i = i4 * 4;
  const int b = (int)(i >> 22);     // N*N = 2^22
  const int col = (int)(i & 2047);  // e index (multiple of 4)
  float4 s = reinterpret_cast<const float4*>(S)[i4];
  float4 m4 = *reinterpret_cast<const float4*>(&Mx[(long)b * ND + col]);
  float4 r4 = *reinterpret_cast<const float4*>(&Rs[(long)b * ND + col]);
  f16x4 o;
  o.x = (f16)(__expf(s.x - m4.x) * r4.x);
  o.y = (f16)(__expf(s.y - m4.y) * r4.y);
  o.z = (f16)(__expf(s.z - m4.z) * r4.z);
  o.w = (f16)(__expf(s.w - m4.w) * r4.w);
  reinterpret_cast<f16x4*>(A)[i4] = o;
}

// ---------------- launch ----------------
extern "C" void kernel_launch(void* const* d_in, const int* in_sizes, int n_in,
                              void* d_out, int out_size, void* d_ws, size_t ws_size,
                              hipStream_t stream) {
  (void)in_sizes; (void)n_in; (void)out_size;
  const float* X = (const float*)d_in[0];      // [8,2048,2048]
  const float* W = (const float*)d_in[1];      // [2048,2048]
  const float* bias = (const float*)d_in[2];   // [2048]
  const float* gamma = (const float*)d_in[3];  // scalar

  char* ws = (char*)d_ws;
  f16* Xh = (f16*)(ws);                      // 67,108,864 B
  f16* Wh = (f16*)(ws + 67108864L);          //  8,388,608 B
  f16* Qh = (f16*)(ws + 75497472L);          // 67,108,864 B
  float* S = (float*)(ws + 142606336L);      // 134,217,728 B
  float* Mp = (float*)(ws + 276824064L);     //    524,288 B
  float* Sp = (float*)(ws + 277348352L);     //    524,288 B
  float* Mx = (float*)(ws + 277872640L);     //     65,536 B
  float* Rs = (float*)(ws + 277938176L);     //     65,536 B
  f16* Amat = Qh;  // overlay: Q dead after GEMM2 (stream-ordered)
  if (ws_size < 278003712UL) return;

  cvt_f16<<<32768, 256, 0, stream>>>(X, Xh, 8388608);
  cvt_f16<<<4096, 256, 0, stream>>>(W, Wh, 1048576);

  dim3 gg(8, 8, 8), bb(512);
  // Q[b,n,f] = sum_e X[b,n,e] W[f,e] + bias[f]  -> fp16
  gemm256<1><<<gg, bb, 0, stream>>>(Xh, NNL, Wh, 0L, bias, nullptr, nullptr, Qh);
  // S[b,n,m] = sum_e Q[b,n,e] X[b,m,e] + gamma  -> fp32
  gemm256<0><<<gg, bb, 0, stream>>>(Qh, NNL, Xh, NNL, nullptr, gamma, S, nullptr);
  stats_partial<<<dim3(8, 8, 8), 256, 0, stream>>>(S, Mp, Sp);
  stats_combine<<<dim3(8, 8), 256, 0, stream>>>(Mp, Sp, Mx, Rs);
  scale_exp_kernel<<<32768, 256, 0, stream>>>(S, Mx, Rs, Amat);
  // out[b,n,m] = sum_e X[b,n,e] attn[b,m,e]  -> fp32 d_out
  gemm256<0><<<gg, bb, 0, stream>>>(Xh, NNL, Amat, NNL, nullptr, nullptr,
                                    (float*)d_out, nullptr);
}